// Round 8
// baseline (770.043 us; speedup 1.0000x reference)
//
#include <hip/hip_runtime.h>

typedef float  f32x4  __attribute__((ext_vector_type(4)));
typedef short  bf16x8 __attribute__((ext_vector_type(8)));
typedef unsigned int   u32;
typedef unsigned short u16;

#define N_NODES 30000
#define N_EDGES 480000
#define VOCABSZ 10000
#define LOG2E 1.442695040888963f

__device__ __forceinline__ float sigm(float x){
  return __builtin_amdgcn_rcpf(1.f + __builtin_amdgcn_exp2f(-LOG2E*x));
}
__device__ __forceinline__ float tanh_(float x){
  return 1.f - 2.f*__builtin_amdgcn_rcpf(1.f + __builtin_amdgcn_exp2f((2.f*LOG2E)*x));
}
__device__ __forceinline__ u16 f2bf(float f){   // round-to-nearest-even bf16
  u32 u = __builtin_bit_cast(u32, f);
  u = u + 0x7fffu + ((u>>16)&1u);
  return (u16)(u>>16);
}
__device__ __forceinline__ float bflo(u32 u){ return __builtin_bit_cast(float, u<<16); }
__device__ __forceinline__ float bfhi(u32 u){ return __builtin_bit_cast(float, u & 0xffff0000u); }

// ---------------------------------------------------------------------------
// W_r = sum_b wcomp[r,b] * basis[b]  -> stored [r][i][o] f32 (GEMM-B layout)
// ---------------------------------------------------------------------------
__global__ __launch_bounds__(256) void wmat_kernel(
    const float* __restrict__ b0, const float* __restrict__ c0,
    const float* __restrict__ b1, const float* __restrict__ c1,
    const float* __restrict__ b2, const float* __restrict__ c2,
    float* __restrict__ W0, float* __restrict__ W1, float* __restrict__ W2)
{
  int id = blockIdx.x*256 + threadIdx.x;
  if (id < 32768){
    int r = id>>12;
    float s = 0.f;
    #pragma unroll
    for (int b=0;b<4;++b) s += c0[r*4+b]*b0[b*4096 + (id&4095)];
    W0[id] = s;
  } else if (id < 65536){
    int k = id - 32768;
    int r = k>>12;
    float s = 0.f;
    #pragma unroll
    for (int b=0;b<4;++b) s += c1[r*4+b]*b1[b*4096 + (k&4095)];
    W1[k] = s;
  } else if (id < 73728){
    int k = id - 65536;
    int r = k>>10;
    float s = 0.f;
    #pragma unroll
    for (int b=0;b<4;++b) s += c2[r*4+b]*b2[b*1024 + (k&1023)];
    W2[k] = s;
  }
}

// ---------------------------------------------------------------------------
// emb_proj: bf16 table [v][512] in GATHER-FRIENDLY order:
//   original j = g*128 + w*16 + g4*4 + jl  ->  j' = w*64 + g4*16 + jl*4 + g
// grid (157, 4): blockIdx.y covers 4 of the 16 jt-chunks.
// ---------------------------------------------------------------------------
__global__ __launch_bounds__(256) void embproj_kernel(
    const float* __restrict__ emb, const float* __restrict__ w_ih,
    const float* __restrict__ b_ih, const float* __restrict__ b_hh,
    u16* __restrict__ eproj)
{
  __shared__ float et[64*132];
  __shared__ float wt[32*132];
  const int tid = threadIdx.x;
  const int v0 = blockIdx.x*64;
  const int vq = tid>>4, jq = tid&15;

  for (int idx = tid*4; idx < 64*128; idx += 1024){
    int row = idx>>7, col = idx&127;
    int vr = v0 + row; if (vr > VOCABSZ-1) vr = VOCABSZ-1;
    *(f32x4*)&et[row*132+col] = *(const f32x4*)&emb[vr*128+col];
  }
  for (int jt = blockIdx.y*4; jt < blockIdx.y*4 + 4; ++jt){
    __syncthreads();
    for (int idx = tid*4; idx < 32*128; idx += 1024){
      int row = idx>>7, col = idx&127;
      *(f32x4*)&wt[row*132+col] = *(const f32x4*)&w_ih[(jt*32+row)*128+col];
    }
    __syncthreads();
    float acc[4][2] = {};
    #pragma unroll 4
    for (int k=0;k<128;++k){
      float w0v = wt[(jq*2+0)*132+k];
      float w1v = wt[(jq*2+1)*132+k];
      #pragma unroll
      for (int a=0;a<4;++a){
        float e = et[(vq*4+a)*132+k];
        acc[a][0] += e*w0v;
        acc[a][1] += e*w1v;
      }
    }
    int jb = jt*32 + jq*2;
    float bi0 = b_ih[jb]   + b_hh[jb];
    float bi1 = b_ih[jb+1] + b_hh[jb+1];
    // j -> j' mapping (jb even => second value lands at j'+4)
    int g  = jb>>7, rem = jb&127;
    int w  = rem>>4, q4 = (rem>>2)&3, jl = rem&3;
    int jp = w*64 + q4*16 + jl*4 + g;
    #pragma unroll
    for (int a=0;a<4;++a){
      int v = v0 + vq*4 + a;
      if (v < VOCABSZ){
        eproj[v*512 + jp]     = f2bf(acc[a][0]+bi0);
        eproj[v*512 + jp + 4] = f2bf(acc[a][1]+bi1);
      }
    }
  }
}

// ---------------------------------------------------------------------------
// Fused 32-step reverse LSTM + fc epilogue.  16 nodes/block (nt=1), 8 waves,
// grid 1875, (512,4): 2 blocks/CU, ~110 VGPR -> NO spill.
// w_hh A-frags resident; h bf16 XOR-swizzled dbuf LDS (4KB x2); rolling
// full-step eproj gather prefetch (8 regs).
// ---------------------------------------------------------------------------
__global__ __launch_bounds__(512, 4) void lstm_kernel(
    const int* __restrict__ tok, const u16* __restrict__ eproj,
    const float* __restrict__ w_hh, const float* __restrict__ fc_w,
    const float* __restrict__ fc_b, float* __restrict__ feats)
{
  __shared__ __align__(16) char lds[8192];      // h dbuf: 2 x 4096
  __shared__ u16 tokL[16*33];
  const int tid = threadIdx.x;
  const int wave = tid>>6, lane = tid&63;
  const int c16 = lane&15, g4 = lane>>4;
  const int nb = blockIdx.x*16;

  // persistent w_hh A-fragments: j = g*128 + wave*16 + c16 ; k = kk*32+8*g4+i
  bf16x8 afr[4][4];
  #pragma unroll
  for (int g=0; g<4; ++g){
    const float* wr = w_hh + (g*128 + wave*16 + c16)*128 + g4*8;
    #pragma unroll
    for (int kk=0; kk<4; ++kk){
      f32x4 wa = *(const f32x4*)(wr + kk*32);
      f32x4 wbv = *(const f32x4*)(wr + kk*32 + 4);
      bf16x8 a;
      a[0]=(short)f2bf(wa[0]); a[1]=(short)f2bf(wa[1]);
      a[2]=(short)f2bf(wa[2]); a[3]=(short)f2bf(wa[3]);
      a[4]=(short)f2bf(wbv[0]); a[5]=(short)f2bf(wbv[1]);
      a[6]=(short)f2bf(wbv[2]); a[7]=(short)f2bf(wbv[3]);
      afr[g][kk] = a;
    }
  }
  if (tid < 256){ // zero h buffer 0 (4KB)
    if (tid < 128){
      f32x4 z = {0.f,0.f,0.f,0.f};
      *(f32x4*)(lds + tid*32) = z;
      *(f32x4*)(lds + tid*32 + 16) = z;
    }
  } else { // stage tokens as u16: tokL[n][33] (padded); tid-256 in 0..255
    int k = tid - 256;           // n = k>>4 (0..15), t = (k&15)*2
    int n = k>>4, t0 = (k&15)*2;
    int node = nb + n;
    int2 a = *(const int2*)(tok + node*32 + t0);
    tokL[n*33 + t0    ] = (u16)a.x;
    tokL[n*33 + t0 + 1] = (u16)a.y;
  }
  const int swz = (c16&7)<<4;
  int rb[4];
  #pragma unroll
  for (int kk=0;kk<4;++kk) rb[kk] = c16*256 + ((kk*64 + g4*16)^swz);
  const int wbB = c16*256 + ((wave*32 + g4*8)^swz);

  float creg[4];
  #pragma unroll
  for (int q=0;q<4;++q) creg[q]=0.f;

  __syncthreads();

  const size_t gbase = (size_t)(wave*128 + g4*32);
  uint4 gxX, gxY;
  {                                       // initial gather (t=0, t'=31)
    int ptok = tokL[c16*33 + 31];
    const char* ep = (const char*)eproj + (size_t)ptok*1024 + gbase;
    gxX = *(const uint4*)ep;
    gxY = *(const uint4*)(ep+16);
  }

  for (int t=0; t<32; ++t){
    const int bufR = (t&1)<<12, bufW = bufR ^ 4096;
    uint4 X = gxX, Y = gxY;
    f32x4 acc[4];
    acc[0][0]=bflo(X.x); acc[1][0]=bfhi(X.x); acc[2][0]=bflo(X.y); acc[3][0]=bfhi(X.y);
    acc[0][1]=bflo(X.z); acc[1][1]=bfhi(X.z); acc[2][1]=bflo(X.w); acc[3][1]=bfhi(X.w);
    acc[0][2]=bflo(Y.x); acc[1][2]=bfhi(Y.x); acc[2][2]=bflo(Y.y); acc[3][2]=bfhi(Y.y);
    acc[0][3]=bflo(Y.z); acc[1][3]=bfhi(Y.z); acc[2][3]=bflo(Y.w); acc[3][3]=bfhi(Y.w);
    if (t < 31){                          // rolling prefetch: next step
      int ptok = tokL[c16*33 + 30 - t];
      const char* ep = (const char*)eproj + (size_t)ptok*1024 + gbase;
      gxX = *(const uint4*)ep;
      gxY = *(const uint4*)(ep+16);
    }
    #pragma unroll
    for (int kk=0;kk<4;++kk){             // per-kk B-frag: 1 transient reg set
      bf16x8 b = *(const bf16x8*)(lds + bufR + rb[kk]);
      acc[0] = __builtin_amdgcn_mfma_f32_16x16x32_bf16(afr[0][kk], b, acc[0], 0,0,0);
      acc[1] = __builtin_amdgcn_mfma_f32_16x16x32_bf16(afr[1][kk], b, acc[1], 0,0,0);
      acc[2] = __builtin_amdgcn_mfma_f32_16x16x32_bf16(afr[2][kk], b, acc[2], 0,0,0);
      acc[3] = __builtin_amdgcn_mfma_f32_16x16x32_bf16(afr[3][kk], b, acc[3], 0,0,0);
    }
    float hv[4];
    #pragma unroll
    for (int q=0;q<4;++q){          // gates: i,f,g,o
      float zi=acc[0][q], zf=acc[1][q], zg=acc[2][q], zo=acc[3][q];
      float cn = sigm(zf)*creg[q] + sigm(zi)*tanh_(zg);
      creg[q] = cn;
      hv[q] = sigm(zo)*tanh_(cn);
    }
    u32 plo, phi;
    asm("v_cvt_pk_bf16_f32 %0, %1, %2" : "=v"(plo) : "v"(hv[0]), "v"(hv[1]));
    asm("v_cvt_pk_bf16_f32 %0, %1, %2" : "=v"(phi) : "v"(hv[2]), "v"(hv[3]));
    uint2 hw; hw.x = plo; hw.y = phi;
    *(uint2*)(lds + bufW + wbB) = hw;
    __syncthreads();
  }
  // fc epilogue: final h in buffer 0; waves 0-3 each compute one out-tile
  if (wave < 4){
    const int ot = wave;
    f32x4 fca;
    fca[0]=0.f; fca[1]=0.f; fca[2]=0.f; fca[3]=0.f;
    #pragma unroll
    for (int kk=0;kk<4;++kk){
      bf16x8 b = *(const bf16x8*)(lds + rb[kk]);
      const float* fr = fc_w + (ot*16 + c16)*128 + kk*32 + g4*8;
      f32x4 wa = *(const f32x4*)fr;
      f32x4 wbv = *(const f32x4*)(fr+4);
      bf16x8 a;
      a[0]=(short)f2bf(wa[0]); a[1]=(short)f2bf(wa[1]);
      a[2]=(short)f2bf(wa[2]); a[3]=(short)f2bf(wa[3]);
      a[4]=(short)f2bf(wbv[0]); a[5]=(short)f2bf(wbv[1]);
      a[6]=(short)f2bf(wbv[2]); a[7]=(short)f2bf(wbv[3]);
      fca = __builtin_amdgcn_mfma_f32_16x16x32_bf16(a, b, fca, 0,0,0);
    }
    const int node = nb + c16;
    #pragma unroll
    for (int q=0;q<4;++q){
      int o = ot*16 + g4*4 + q;
      feats[node*64 + o] = fca[q] + fc_b[o];
    }
  }
}

// ---------------------------------------------------------------------------
// CSR build: histogram -> block scan -> sorted-edge permutation
// ---------------------------------------------------------------------------
__global__ __launch_bounds__(256) void hist_kernel(
    const int* __restrict__ dst, int* __restrict__ cnt, int n)
{
  int e = blockIdx.x*256 + threadIdx.x;
  if (e < n) atomicAdd(&cnt[dst[e]], 1);
}

__global__ __launch_bounds__(1024) void scan_kernel(
    int* __restrict__ cnt, int* __restrict__ ofs)   // cnt doubles as "cur"
{
  __shared__ int sums[1024];
  const int tid = threadIdx.x;
  const int base = tid*30;                          // 1024*30 = 30720 >= 30001
  int loc[30]; int s = 0;
  #pragma unroll
  for (int i=0;i<30;++i){
    int d = base + i;
    int c = (d < N_NODES) ? cnt[d] : 0;
    loc[i] = s; s += c;
  }
  sums[tid] = s;
  __syncthreads();
  for (int off=1; off<1024; off<<=1){
    int v = (tid >= off) ? sums[tid-off] : 0;
    __syncthreads();
    sums[tid] += v;
    __syncthreads();
  }
  int excl = sums[tid] - s;
  #pragma unroll
  for (int i=0;i<30;++i){
    int d = base + i;
    if (d <= N_NODES){
      int v = excl + loc[i];
      ofs[d] = v;
      if (d < N_NODES) cnt[d] = v;                  // reset cur = segment start
    }
  }
}

__global__ __launch_bounds__(256) void permute_kernel(
    const int* __restrict__ dst, const int* __restrict__ src,
    const int* __restrict__ rel, const float* __restrict__ enorm,
    int* __restrict__ cur, u32* __restrict__ esr, float* __restrict__ esn,
    int n)
{
  int e = blockIdx.x*256 + threadIdx.x;
  if (e < n){
    int p = atomicAdd(&cur[dst[e]], 1);
    esr[p] = (u32)src[e] | ((u32)rel[e] << 16);
    esn[p] = enorm[e];
  }
}

// ---------------------------------------------------------------------------
// Aggregate (CSR gather, atomic-free): wave per dst,
//   agg[d][r][o] = sum_{e: dst=d, rel=r} (relu? h[src])[o] * norm
// 8 rel accumulators in registers; uniform switch on rel (rule #20 safe).
// ---------------------------------------------------------------------------
template<bool RELU>
__global__ __launch_bounds__(256) void aggregate_kernel(
    const float* __restrict__ h, const u32* __restrict__ esr,
    const float* __restrict__ esn, const int* __restrict__ ofs,
    float* __restrict__ agg)
{
  const int lane = threadIdx.x & 63;
  const int d = (blockIdx.x*256 + threadIdx.x) >> 6;
  if (d >= N_NODES) return;
  const int beg = ofs[d], end = ofs[d+1];
  float a0=0.f,a1=0.f,a2=0.f,a3=0.f,a4=0.f,a5=0.f,a6=0.f,a7=0.f;
  if (beg < end){
    u32 sr = esr[beg]; float nm = esn[beg];
    float v = h[(size_t)(sr & 0xffff)*64 + lane];
    if (RELU) v = fmaxf(v, 0.f);
    for (int i = beg; i < end; ){
      ++i;
      u32 sr1 = 0; float nm1 = 0.f, v1 = 0.f;
      if (i < end){
        sr1 = esr[i]; nm1 = esn[i];
        v1 = h[(size_t)(sr1 & 0xffff)*64 + lane];
        if (RELU) v1 = fmaxf(v1, 0.f);
      }
      float m = v*nm;
      int r = __builtin_amdgcn_readfirstlane((int)(sr >> 16));
      switch(r){
        case 0: a0 += m; break;  case 1: a1 += m; break;
        case 2: a2 += m; break;  case 3: a3 += m; break;
        case 4: a4 += m; break;  case 5: a5 += m; break;
        case 6: a6 += m; break;  default: a7 += m; break;
      }
      sr = sr1; nm = nm1; v = v1;
    }
  }
  float* out = agg + (size_t)d*512 + lane;
  out[0]=a0; out[64]=a1; out[128]=a2; out[192]=a3;
  out[256]=a4; out[320]=a5; out[384]=a6; out[448]=a7;
}

// ---------------------------------------------------------------------------
// Transform: out[n][o] = sum_k agg[n][k] * W[k][o]   (K=512, f32 GEMM)
// block = 256 thr, 64 nodes; NO=64: 4n x 4o per thread; NO=16: 1n x 4o.
// ---------------------------------------------------------------------------
template<int NO>
__global__ __launch_bounds__(256) void transform_kernel(
    const float* __restrict__ agg, const float* __restrict__ W,
    float* __restrict__ out)
{
  const int tid = threadIdx.x;
  const int n0 = blockIdx.x*64;
  __shared__ float As[64][68];
  if (NO == 64){
    __shared__ float Bs[64][68];
    const int tx = tid&15, ty = tid>>4;
    float acc[4][4] = {};
    for (int kt=0; kt<8; ++kt){
      __syncthreads();
      for (int idx = tid*4; idx < 4096; idx += 1024){
        int rr = idx>>6, cc = idx&63;
        int n = n0 + rr; if (n > N_NODES-1) n = N_NODES-1;
        *(f32x4*)&As[rr][cc] = *(const f32x4*)(agg + (size_t)n*512 + kt*64 + cc);
      }
      for (int idx = tid*4; idx < 4096; idx += 1024){
        int kk = idx>>6, oo = idx&63;
        *(f32x4*)&Bs[kk][oo] = *(const f32x4*)(W + (size_t)(kt*64+kk)*64 + oo);
      }
      __syncthreads();
      #pragma unroll 8
      for (int k=0;k<64;++k){
        f32x4 b4 = *(const f32x4*)&Bs[k][tx*4];
        #pragma unroll
        for (int i=0;i<4;++i){
          float a = As[ty*4+i][k];
          acc[i][0] += a*b4[0]; acc[i][1] += a*b4[1];
          acc[i][2] += a*b4[2]; acc[i][3] += a*b4[3];
        }
      }
    }
    #pragma unroll
    for (int i=0;i<4;++i){
      int n = n0 + ty*4 + i;
      if (n < N_NODES)
        *(f32x4*)(out + (size_t)n*64 + tx*4) = *(f32x4*)&acc[i][0];
    }
  } else {          // NO == 16: W (512x16 = 32KB) fully LDS-resident
    __shared__ float Bs2[512][16];
    const int tx = tid&3, ty = tid>>2;
    for (int idx = tid*4; idx < 8192; idx += 1024)
      *(f32x4*)&Bs2[idx>>4][idx&15] = *(const f32x4*)(W + idx);
    float acc[4] = {};
    for (int kt=0; kt<8; ++kt){
      __syncthreads();
      for (int idx = tid*4; idx < 4096; idx += 1024){
        int rr = idx>>6, cc = idx&63;
        int n = n0 + rr; if (n > N_NODES-1) n = N_NODES-1;
        *(f32x4*)&As[rr][cc] = *(const f32x4*)(agg + (size_t)n*512 + kt*64 + cc);
      }
      __syncthreads();
      #pragma unroll 8
      for (int k=0;k<64;++k){
        float a = As[ty][k];
        f32x4 b4 = *(const f32x4*)&Bs2[kt*64+k][tx*4];
        acc[0] += a*b4[0]; acc[1] += a*b4[1];
        acc[2] += a*b4[2]; acc[3] += a*b4[3];
      }
    }
    int n = n0 + ty;
    if (n < N_NODES)
      *(f32x4*)(out + (size_t)n*16 + tx*4) = *(f32x4*)&acc[0];
  }
}

// ---------------------------------------------------------------------------
extern "C" void kernel_launch(void* const* d_in, const int* in_sizes, int n_in,
                              void* d_out, int out_size, void* d_ws, size_t ws_size,
                              hipStream_t stream)
{
  const int*   tok    = (const int*)  d_in[0];
  const int*   src    = (const int*)  d_in[2];
  const int*   dst    = (const int*)  d_in[3];
  const int*   rel    = (const int*)  d_in[4];
  const float* enorm  = (const float*)d_in[5];
  const float* emb    = (const float*)d_in[6];
  const float* w_ih   = (const float*)d_in[7];
  const float* w_hh   = (const float*)d_in[8];
  const float* b_ih   = (const float*)d_in[9];
  const float* b_hh   = (const float*)d_in[10];
  const float* fc_w   = (const float*)d_in[11];
  const float* fc_b   = (const float*)d_in[12];
  const float* basis0 = (const float*)d_in[13];
  const float* wcomp0 = (const float*)d_in[14];
  const float* basis1 = (const float*)d_in[15];
  const float* wcomp1 = (const float*)d_in[16];
  const float* basis2 = (const float*)d_in[17];
  const float* wcomp2 = (const float*)d_in[18];

  char* ws = (char*)d_ws;
  // agg [0, 61.44M); eproj (10.24M) overlaps its head [dead after lstm];
  // cur (120KB @ +20M, inside agg) [dead after permute, before agg written]
  float* agg   = (float*)(ws);                 // 61,440,000 B
  u16*   eproj = (u16*)  (ws);                 // 10,240,000 B (inside agg)
  int*   cur   = (int*)  (ws + 20000000);      //    120,004 B (inside agg)
  float* feats = (float*)(ws + 61440000);      //  7,680,000 B (g2 reuses this)
  float* g2    = (float*)(ws + 61440000);
  float* g1    = (float*)(ws + 69120000);      //  7,680,000 B
  int*   ofs   = (int*)  (ws + 76800000);      //    120,064 B
  u32*   esr   = (u32*)  (ws + 76920064);      //  1,920,000 B
  float* esn   = (float*)(ws + 78840064);      //  1,920,000 B
  float* W0    = (float*)(ws + 80760064);      //    131,072 B
  float* W1    = (float*)(ws + 80891136);      //    131,072 B
  float* W2    = (float*)(ws + 81022208);      //     32,768 B

  // CSR build first (independent of everything downstream of dst/src/rel)
  hipMemsetAsync(cur, 0, 120004, stream);
  hist_kernel<<<1875, 256, 0, stream>>>(dst, cur, N_EDGES);
  scan_kernel<<<1, 1024, 0, stream>>>(cur, ofs);
  permute_kernel<<<1875, 256, 0, stream>>>(dst, src, rel, enorm, cur, esr, esn, N_EDGES);

  wmat_kernel<<<288, 256, 0, stream>>>(basis0, wcomp0, basis1, wcomp1,
                                       basis2, wcomp2, W0, W1, W2);
  embproj_kernel<<<dim3(157,4), 256, 0, stream>>>(emb, w_ih, b_ih, b_hh, eproj);
  lstm_kernel<<<1875, 512, 0, stream>>>(tok, eproj, w_hh, fc_w, fc_b, feats);

  // layer 0: feats -> agg -> g1
  aggregate_kernel<false><<<7500, 256, 0, stream>>>(feats, esr, esn, ofs, agg);
  transform_kernel<64><<<469, 256, 0, stream>>>(agg, W0, g1);

  // layer 1: relu(g1) -> agg -> g2 (g2 overwrites dead feats)
  aggregate_kernel<true><<<7500, 256, 0, stream>>>(g1, esr, esn, ofs, agg);
  transform_kernel<64><<<469, 256, 0, stream>>>(agg, W1, g2);

  // layer 2: relu(g2) -> agg -> out
  aggregate_kernel<true><<<7500, 256, 0, stream>>>(g2, esr, esn, ofs, agg);
  transform_kernel<16><<<469, 256, 0, stream>>>(agg, W2, (float*)d_out);
}

// Round 9
// 674.868 us; speedup vs baseline: 1.1410x; 1.1410x over previous
//
#include <hip/hip_runtime.h>

typedef float  f32x4  __attribute__((ext_vector_type(4)));
typedef short  bf16x8 __attribute__((ext_vector_type(8)));
typedef unsigned int   u32;
typedef unsigned short u16;

#define N_NODES 30000
#define N_EDGES 480000
#define VOCABSZ 10000
#define LOG2E 1.442695040888963f

__device__ __forceinline__ float sigm(float x){
  return __builtin_amdgcn_rcpf(1.f + __builtin_amdgcn_exp2f(-LOG2E*x));
}
__device__ __forceinline__ float tanh_(float x){
  return 1.f - 2.f*__builtin_amdgcn_rcpf(1.f + __builtin_amdgcn_exp2f((2.f*LOG2E)*x));
}
__device__ __forceinline__ u16 f2bf(float f){   // round-to-nearest-even bf16
  u32 u = __builtin_bit_cast(u32, f);
  u = u + 0x7fffu + ((u>>16)&1u);
  return (u16)(u>>16);
}
__device__ __forceinline__ float bflo(u32 u){ return __builtin_bit_cast(float, u<<16); }
__device__ __forceinline__ float bfhi(u32 u){ return __builtin_bit_cast(float, u & 0xffff0000u); }

// ---------------------------------------------------------------------------
// W_r = sum_b wcomp[r,b] * basis[b]  -> stored [r][i][o] f32 (GEMM-B layout)
// ---------------------------------------------------------------------------
__global__ __launch_bounds__(256) void wmat_kernel(
    const float* __restrict__ b0, const float* __restrict__ c0,
    const float* __restrict__ b1, const float* __restrict__ c1,
    const float* __restrict__ b2, const float* __restrict__ c2,
    float* __restrict__ W0, float* __restrict__ W1, float* __restrict__ W2)
{
  int id = blockIdx.x*256 + threadIdx.x;
  if (id < 32768){
    int r = id>>12;
    float s = 0.f;
    #pragma unroll
    for (int b=0;b<4;++b) s += c0[r*4+b]*b0[b*4096 + (id&4095)];
    W0[id] = s;
  } else if (id < 65536){
    int k = id - 32768;
    int r = k>>12;
    float s = 0.f;
    #pragma unroll
    for (int b=0;b<4;++b) s += c1[r*4+b]*b1[b*4096 + (k&4095)];
    W1[k] = s;
  } else if (id < 73728){
    int k = id - 65536;
    int r = k>>10;
    float s = 0.f;
    #pragma unroll
    for (int b=0;b<4;++b) s += c2[r*4+b]*b2[b*1024 + (k&1023)];
    W2[k] = s;
  }
}

// ---------------------------------------------------------------------------
// emb_proj: bf16 table [v][512] in GATHER-FRIENDLY order:
//   original j = g*128 + w*16 + g4*4 + jl  ->  j' = w*64 + g4*16 + jl*4 + g
// grid (157, 4): blockIdx.y covers 4 of the 16 jt-chunks.
// ---------------------------------------------------------------------------
__global__ __launch_bounds__(256) void embproj_kernel(
    const float* __restrict__ emb, const float* __restrict__ w_ih,
    const float* __restrict__ b_ih, const float* __restrict__ b_hh,
    u16* __restrict__ eproj)
{
  __shared__ float et[64*132];
  __shared__ float wt[32*132];
  const int tid = threadIdx.x;
  const int v0 = blockIdx.x*64;
  const int vq = tid>>4, jq = tid&15;

  for (int idx = tid*4; idx < 64*128; idx += 1024){
    int row = idx>>7, col = idx&127;
    int vr = v0 + row; if (vr > VOCABSZ-1) vr = VOCABSZ-1;
    *(f32x4*)&et[row*132+col] = *(const f32x4*)&emb[vr*128+col];
  }
  for (int jt = blockIdx.y*4; jt < blockIdx.y*4 + 4; ++jt){
    __syncthreads();
    for (int idx = tid*4; idx < 32*128; idx += 1024){
      int row = idx>>7, col = idx&127;
      *(f32x4*)&wt[row*132+col] = *(const f32x4*)&w_ih[(jt*32+row)*128+col];
    }
    __syncthreads();
    float acc[4][2] = {};
    #pragma unroll 4
    for (int k=0;k<128;++k){
      float w0v = wt[(jq*2+0)*132+k];
      float w1v = wt[(jq*2+1)*132+k];
      #pragma unroll
      for (int a=0;a<4;++a){
        float e = et[(vq*4+a)*132+k];
        acc[a][0] += e*w0v;
        acc[a][1] += e*w1v;
      }
    }
    int jb = jt*32 + jq*2;
    float bi0 = b_ih[jb]   + b_hh[jb];
    float bi1 = b_ih[jb+1] + b_hh[jb+1];
    // j -> j' mapping (jb even => second value lands at j'+4)
    int g  = jb>>7, rem = jb&127;
    int w  = rem>>4, q4 = (rem>>2)&3, jl = rem&3;
    int jp = w*64 + q4*16 + jl*4 + g;
    #pragma unroll
    for (int a=0;a<4;++a){
      int v = v0 + vq*4 + a;
      if (v < VOCABSZ){
        eproj[v*512 + jp]     = f2bf(acc[a][0]+bi0);
        eproj[v*512 + jp + 4] = f2bf(acc[a][1]+bi1);
      }
    }
  }
}

// ---------------------------------------------------------------------------
// Fused 32-step reverse LSTM + fc epilogue.  64 nodes/block, 8 waves, grid 469.
// (512,2): no reg cap -> no spill (r5-measured config, ~260us).
// Wave w owns j-slice [16w,16w+16) of all 4 gates; w_hh A-frags in registers;
// h (bf16, XOR-swizzled) streams via dbuf LDS; rolling full-step gather
// prefetch from the pre-projected eproj table.
// ---------------------------------------------------------------------------
__global__ __launch_bounds__(512, 2) void lstm_kernel(
    const int* __restrict__ tok, const u16* __restrict__ eproj,
    const float* __restrict__ w_hh, const float* __restrict__ fc_w,
    const float* __restrict__ fc_b, float* __restrict__ feats)
{
  __shared__ __align__(16) char lds[32768];
  __shared__ u16 tokL[64*33];
  const int tid = threadIdx.x;
  const int wave = tid>>6, lane = tid&63;
  const int c16 = lane&15, g4 = lane>>4;
  const int nb = blockIdx.x*64;

  // persistent w_hh A-fragments: j = g*128 + wave*16 + c16 ; k = kk*32+8*g4+i
  bf16x8 afr[4][4];
  #pragma unroll
  for (int g=0; g<4; ++g){
    const float* wr = w_hh + (g*128 + wave*16 + c16)*128 + g4*8;
    #pragma unroll
    for (int kk=0; kk<4; ++kk){
      f32x4 wa = *(const f32x4*)(wr + kk*32);
      f32x4 wbv = *(const f32x4*)(wr + kk*32 + 4);
      bf16x8 a;
      a[0]=(short)f2bf(wa[0]); a[1]=(short)f2bf(wa[1]);
      a[2]=(short)f2bf(wa[2]); a[3]=(short)f2bf(wa[3]);
      a[4]=(short)f2bf(wbv[0]); a[5]=(short)f2bf(wbv[1]);
      a[6]=(short)f2bf(wbv[2]); a[7]=(short)f2bf(wbv[3]);
      afr[g][kk] = a;
    }
  }
  { // zero h buffer 0 (8KB used per buffer half)
    f32x4 z = {0.f,0.f,0.f,0.f};
    for (int i = tid*16; i < 16384; i += 8192) *(f32x4*)(lds + i) = z;
  }
  { // stage tokens as u16: tokL[n][33] (padded)
    int n = tid>>3, t0 = (tid&7)*4;
    int node = nb + n; if (node > N_NODES-1) node = N_NODES-1;
    int4 a = *(const int4*)(tok + node*32 + t0);
    tokL[n*33 + t0    ] = (u16)a.x;
    tokL[n*33 + t0 + 1] = (u16)a.y;
    tokL[n*33 + t0 + 2] = (u16)a.z;
    tokL[n*33 + t0 + 3] = (u16)a.w;
  }
  const int swz = (c16&7)<<4;
  int rb[4];
  #pragma unroll
  for (int kk=0;kk<4;++kk) rb[kk] = c16*256 + ((kk*64 + g4*16)^swz);
  const int wbB = c16*256 + ((wave*32 + g4*8)^swz);

  float creg[4][4];
  #pragma unroll
  for (int nt=0;nt<4;++nt)
    #pragma unroll
    for (int q=0;q<4;++q) creg[nt][q]=0.f;

  __syncthreads();

  const size_t gbase = (size_t)(wave*128 + g4*32);
  uint4 gxX[4], gxY[4];
  #pragma unroll
  for (int nt=0;nt<4;++nt){                 // initial gathers (t=0, t'=31)
    int ptok = tokL[(nt*16+c16)*33 + 31];
    const char* ep = (const char*)eproj + (size_t)ptok*1024 + gbase;
    gxX[nt] = *(const uint4*)ep;
    gxY[nt] = *(const uint4*)(ep+16);
  }

  for (int t=0; t<32; ++t){
    const int bufR = (t&1)<<14, bufW = bufR ^ 16384;
    #pragma unroll
    for (int nt=0; nt<4; ++nt){
      uint4 X = gxX[nt], Y = gxY[nt];
      f32x4 acc[4];
      acc[0][0]=bflo(X.x); acc[1][0]=bfhi(X.x); acc[2][0]=bflo(X.y); acc[3][0]=bfhi(X.y);
      acc[0][1]=bflo(X.z); acc[1][1]=bfhi(X.z); acc[2][1]=bflo(X.w); acc[3][1]=bfhi(X.w);
      acc[0][2]=bflo(Y.x); acc[1][2]=bfhi(Y.x); acc[2][2]=bflo(Y.y); acc[3][2]=bfhi(Y.y);
      acc[0][3]=bflo(Y.z); acc[1][3]=bfhi(Y.z); acc[2][3]=bflo(Y.w); acc[3][3]=bfhi(Y.w);
      if (t < 31){                          // rolling prefetch: next step, same nt
        int ptok = tokL[(nt*16+c16)*33 + 30 - t];
        const char* ep = (const char*)eproj + (size_t)ptok*1024 + gbase;
        gxX[nt] = *(const uint4*)ep;
        gxY[nt] = *(const uint4*)(ep+16);
      }
      bf16x8 bfr[4];
      #pragma unroll
      for (int kk=0;kk<4;++kk)
        bfr[kk] = *(const bf16x8*)(lds + bufR + rb[kk] + nt*4096);
      #pragma unroll
      for (int kk=0;kk<4;++kk){
        acc[0] = __builtin_amdgcn_mfma_f32_16x16x32_bf16(afr[0][kk], bfr[kk], acc[0], 0,0,0);
        acc[1] = __builtin_amdgcn_mfma_f32_16x16x32_bf16(afr[1][kk], bfr[kk], acc[1], 0,0,0);
        acc[2] = __builtin_amdgcn_mfma_f32_16x16x32_bf16(afr[2][kk], bfr[kk], acc[2], 0,0,0);
        acc[3] = __builtin_amdgcn_mfma_f32_16x16x32_bf16(afr[3][kk], bfr[kk], acc[3], 0,0,0);
      }
      float hv[4];
      #pragma unroll
      for (int q=0;q<4;++q){          // gates: i,f,g,o
        float zi=acc[0][q], zf=acc[1][q], zg=acc[2][q], zo=acc[3][q];
        float cn = sigm(zf)*creg[nt][q] + sigm(zi)*tanh_(zg);
        creg[nt][q] = cn;
        hv[q] = sigm(zo)*tanh_(cn);
      }
      u32 plo, phi;
      asm("v_cvt_pk_bf16_f32 %0, %1, %2" : "=v"(plo) : "v"(hv[0]), "v"(hv[1]));
      asm("v_cvt_pk_bf16_f32 %0, %1, %2" : "=v"(phi) : "v"(hv[2]), "v"(hv[3]));
      uint2 hw; hw.x = plo; hw.y = phi;
      *(uint2*)(lds + bufW + wbB + nt*4096) = hw;
    }
    __syncthreads();
  }
  // fc epilogue: final h in buffer 0; wave pair handles node-tile wave>>1,
  // each half covers 2 of the 4 output tiles.
  const int w2 = wave>>1, half = wave&1;
  f32x4 fca[2];
  #pragma unroll
  for (int oi=0;oi<2;++oi){ fca[oi][0]=0.f; fca[oi][1]=0.f; fca[oi][2]=0.f; fca[oi][3]=0.f; }
  #pragma unroll
  for (int kk=0;kk<4;++kk){
    bf16x8 b = *(const bf16x8*)(lds + rb[kk] + w2*4096);
    #pragma unroll
    for (int oi=0;oi<2;++oi){
      int ot = half*2 + oi;
      const float* fr = fc_w + (ot*16 + c16)*128 + kk*32 + g4*8;
      f32x4 wa = *(const f32x4*)fr;
      f32x4 wbv = *(const f32x4*)(fr+4);
      bf16x8 a;
      a[0]=(short)f2bf(wa[0]); a[1]=(short)f2bf(wa[1]);
      a[2]=(short)f2bf(wa[2]); a[3]=(short)f2bf(wa[3]);
      a[4]=(short)f2bf(wbv[0]); a[5]=(short)f2bf(wbv[1]);
      a[6]=(short)f2bf(wbv[2]); a[7]=(short)f2bf(wbv[3]);
      fca[oi] = __builtin_amdgcn_mfma_f32_16x16x32_bf16(a, b, fca[oi], 0,0,0);
    }
  }
  const int node = nb + w2*16 + c16;
  if (node < N_NODES){
    #pragma unroll
    for (int oi=0;oi<2;++oi)
      #pragma unroll
      for (int q=0;q<4;++q){
        int o = (half*2+oi)*16 + g4*4 + q;
        feats[node*64 + o] = fca[oi][q] + fc_b[o];
      }
  }
}

// ---------------------------------------------------------------------------
// CSR build: histogram -> block scan -> sorted-edge permutation
// packed edge word: src (15b) | rel<<15 (3b) | (dst&31)<<18 (5b)
// ---------------------------------------------------------------------------
__global__ __launch_bounds__(256) void hist_kernel(
    const int* __restrict__ dst, int* __restrict__ cnt, int n)
{
  int e = blockIdx.x*256 + threadIdx.x;
  if (e < n) atomicAdd(&cnt[dst[e]], 1);
}

__global__ __launch_bounds__(1024) void scan_kernel(
    int* __restrict__ cnt, int* __restrict__ ofs)   // cnt doubles as "cur"
{
  __shared__ int sums[1024];
  const int tid = threadIdx.x;
  const int base = tid*30;                          // 1024*30 = 30720 >= 30001
  int loc[30]; int s = 0;
  #pragma unroll
  for (int i=0;i<30;++i){
    int d = base + i;
    int c = (d < N_NODES) ? cnt[d] : 0;
    loc[i] = s; s += c;
  }
  sums[tid] = s;
  __syncthreads();
  for (int off=1; off<1024; off<<=1){
    int v = (tid >= off) ? sums[tid-off] : 0;
    __syncthreads();
    sums[tid] += v;
    __syncthreads();
  }
  int excl = sums[tid] - s;
  #pragma unroll
  for (int i=0;i<30;++i){
    int d = base + i;
    if (d <= N_NODES){
      int v = excl + loc[i];
      ofs[d] = v;
      if (d < N_NODES) cnt[d] = v;                  // reset cur = segment start
    }
  }
}

__global__ __launch_bounds__(256) void permute_kernel(
    const int* __restrict__ dst, const int* __restrict__ src,
    const int* __restrict__ rel, const float* __restrict__ enorm,
    int* __restrict__ cur, u32* __restrict__ esr, float* __restrict__ esn,
    int n)
{
  int e = blockIdx.x*256 + threadIdx.x;
  if (e < n){
    int d = dst[e];
    int p = atomicAdd(&cur[d], 1);
    esr[p] = (u32)src[e] | ((u32)rel[e] << 15) | ((u32)(d & 31) << 18);
    esn[p] = enorm[e];
  }
}

// ---------------------------------------------------------------------------
// FUSED RGCN layer: block = 32 dsts.
// Phase 1: gather the block's contiguous CSR edge range (8-deep pipelined
//   h[src] reads), accumulate norm*(relu? h) into LDS A[dloc][rel*64+feat].
// Phase 2: out[32][NO] = A[32][512] @ W[512][NO] from LDS (k-chunked).
// No 61MB intermediate, no atomics.
// ---------------------------------------------------------------------------
template<bool RELU, int NO>
__global__ __launch_bounds__(256, 2) void rgcn_fused(
    const float* __restrict__ h, const u32* __restrict__ esr,
    const float* __restrict__ esn, const int* __restrict__ ofs,
    const float* __restrict__ W, float* __restrict__ out)
{
  __shared__ float A[32][516];                       // 66,048 B
  __shared__ float Bs[32][NO == 64 ? 68 : 18];       // 8,704 / 2,304 B
  const int tid = threadIdx.x;
  const int wave = tid>>6, lane = tid&63;
  const int d0 = blockIdx.x*32;

  // zero A
  for (int idx = tid*4; idx < 32*516; idx += 1024){
    f32x4 z = {0.f,0.f,0.f,0.f};
    *(f32x4*)&A[0][idx] = z;
  }
  __syncthreads();

  // ---- phase 1: per-wave contiguous edge range for dsts [d0+8w, d0+8w+8)
  {
    int dlo = d0 + wave*8;  if (dlo > N_NODES) dlo = N_NODES;
    int dhi = dlo + 8;      if (dhi > N_NODES) dhi = N_NODES;
    const int beg = ofs[dlo], end = ofs[dhi];
    for (int i = beg; i < end; i += 8){
      u32 srb[8]; float nmb[8], vb[8];
      #pragma unroll
      for (int j=0;j<8;++j){
        int ii = i + j;
        int ic = (ii < end) ? ii : (end-1);
        srb[j] = esr[ic];
        nmb[j] = (ii < end) ? esn[ic] : 0.f;
      }
      #pragma unroll
      for (int j=0;j<8;++j)
        vb[j] = h[(size_t)(srb[j] & 0x7fff)*64 + lane];
      #pragma unroll
      for (int j=0;j<8;++j){
        float v = vb[j];
        if (RELU) v = fmaxf(v, 0.f);
        float m = v * nmb[j];
        int dloc = (srb[j] >> 18) & 31;
        int r    = (srb[j] >> 15) & 7;
        A[dloc][r*64 + lane] += m;
      }
    }
  }
  __syncthreads();

  // ---- phase 2: out = A @ W  (k-chunks of 32)
  if (NO == 64){
    const int tx = tid&15, ny = tid>>4;              // 16 o-groups x 16 n
    float acc0[4] = {0.f,0.f,0.f,0.f};
    float acc1[4] = {0.f,0.f,0.f,0.f};
    for (int kt=0; kt<16; ++kt){
      if (kt) __syncthreads();
      for (int idx = tid*4; idx < 2048; idx += 1024){
        int row = idx>>6, col = idx&63;
        *(f32x4*)&Bs[row][col] = *(const f32x4*)(W + (size_t)(kt*32+row)*64 + col);
      }
      __syncthreads();
      #pragma unroll
      for (int kk4=0; kk4<32; kk4+=4){
        f32x4 av0 = *(const f32x4*)&A[ny][kt*32+kk4];
        f32x4 av1 = *(const f32x4*)&A[ny+16][kt*32+kk4];
        #pragma unroll
        for (int q=0;q<4;++q){
          f32x4 b4 = *(const f32x4*)&Bs[kk4+q][tx*4];
          #pragma unroll
          for (int j=0;j<4;++j){
            acc0[j] += av0[q]*b4[j];
            acc1[j] += av1[q]*b4[j];
          }
        }
      }
    }
    int n = d0 + ny;
    if (n < N_NODES){
      f32x4 v; v[0]=acc0[0]; v[1]=acc0[1]; v[2]=acc0[2]; v[3]=acc0[3];
      *(f32x4*)(out + (size_t)n*64 + tx*4) = v;
    }
    n = d0 + ny + 16;
    if (n < N_NODES){
      f32x4 v; v[0]=acc1[0]; v[1]=acc1[1]; v[2]=acc1[2]; v[3]=acc1[3];
      *(f32x4*)(out + (size_t)n*64 + tx*4) = v;
    }
  } else {                                            // NO == 16
    const int o2 = (tid&7)*2, n = tid>>3;             // 8 o-pairs x 32 n
    float acc0 = 0.f, acc1 = 0.f;
    for (int kt=0; kt<16; ++kt){
      if (kt) __syncthreads();
      {
        int idx = tid*2;                              // 256*2 = 512 = 32x16
        int row = idx>>4, col = idx&15;
        float2 w2 = *(const float2*)(W + (size_t)(kt*32+row)*16 + col);
        *(float2*)&Bs[row][col] = w2;
      }
      __syncthreads();
      #pragma unroll
      for (int kk4=0; kk4<32; kk4+=4){
        f32x4 av = *(const f32x4*)&A[n][kt*32+kk4];
        #pragma unroll
        for (int q=0;q<4;++q){
          acc0 += av[q]*Bs[kk4+q][o2];
          acc1 += av[q]*Bs[kk4+q][o2+1];
        }
      }
    }
    int nn = d0 + n;
    if (nn < N_NODES){
      out[(size_t)nn*16 + o2]     = acc0;
      out[(size_t)nn*16 + o2 + 1] = acc1;
    }
  }
}

// ---------------------------------------------------------------------------
extern "C" void kernel_launch(void* const* d_in, const int* in_sizes, int n_in,
                              void* d_out, int out_size, void* d_ws, size_t ws_size,
                              hipStream_t stream)
{
  const int*   tok    = (const int*)  d_in[0];
  const int*   src    = (const int*)  d_in[2];
  const int*   dst    = (const int*)  d_in[3];
  const int*   rel    = (const int*)  d_in[4];
  const float* enorm  = (const float*)d_in[5];
  const float* emb    = (const float*)d_in[6];
  const float* w_ih   = (const float*)d_in[7];
  const float* w_hh   = (const float*)d_in[8];
  const float* b_ih   = (const float*)d_in[9];
  const float* b_hh   = (const float*)d_in[10];
  const float* fc_w   = (const float*)d_in[11];
  const float* fc_b   = (const float*)d_in[12];
  const float* basis0 = (const float*)d_in[13];
  const float* wcomp0 = (const float*)d_in[14];
  const float* basis1 = (const float*)d_in[15];
  const float* wcomp1 = (const float*)d_in[16];
  const float* basis2 = (const float*)d_in[17];
  const float* wcomp2 = (const float*)d_in[18];

  char* ws = (char*)d_ws;
  u16*   eproj = (u16*)  (ws);                 // 10,240,000 B
  float* feats = (float*)(ws + 10240000);      //  7,680,000 B
  float* g1    = (float*)(ws + 17920000);      //  7,680,000 B
  float* g2    = (float*)(ws + 25600000);      //  7,680,000 B
  int*   ofs   = (int*)  (ws + 33280000);      //    120,064 B
  int*   cur   = (int*)  (ws + 33400064);      //    120,064 B
  u32*   esr   = (u32*)  (ws + 33520128);      //  1,920,000 B
  float* esn   = (float*)(ws + 35440128);      //  1,920,000 B
  float* W0    = (float*)(ws + 37360128);      //    131,072 B
  float* W1    = (float*)(ws + 37491200);      //    131,072 B
  float* W2    = (float*)(ws + 37622272);      //     32,768 B

  // CSR build first (independent of the LSTM path)
  hipMemsetAsync(cur, 0, 120004, stream);
  hist_kernel<<<1875, 256, 0, stream>>>(dst, cur, N_EDGES);
  scan_kernel<<<1, 1024, 0, stream>>>(cur, ofs);
  permute_kernel<<<1875, 256, 0, stream>>>(dst, src, rel, enorm, cur, esr, esn, N_EDGES);

  wmat_kernel<<<288, 256, 0, stream>>>(basis0, wcomp0, basis1, wcomp1,
                                       basis2, wcomp2, W0, W1, W2);
  embproj_kernel<<<dim3(157,4), 256, 0, stream>>>(emb, w_ih, b_ih, b_hh, eproj);
  lstm_kernel<<<469, 512, 0, stream>>>(tok, eproj, w_hh, fc_w, fc_b, feats);

  // fused RGCN layers (938 blocks x 32 dsts = 30016 >= 30000)
  rgcn_fused<false,64><<<938, 256, 0, stream>>>(feats, esr, esn, ofs, W0, g1);
  rgcn_fused<true, 64><<<938, 256, 0, stream>>>(g1,    esr, esn, ofs, W1, g2);
  rgcn_fused<true, 16><<<938, 256, 0, stream>>>(g2,    esr, esn, ofs, W2, (float*)d_out);
}